// Round 5
// baseline (8313.123 us; speedup 1.0000x reference)
//
#include <hip/hip_runtime.h>
#include <stdint.h>

// LSTM: T=1024, B=32, I=512, H=512, fp32.
// R5: two-phase single kernel. Phase 0: each block privately computes its
// gx slice (x @ Wih^T + bias) for ALL t — no sync, pure FMA, plain stores
// to a per-block-private d_ws region (self-read-only => same-L2 coherent).
// Phase 1: slim recurrence — serial chain is only h-proj + reduce + act +
// tagged-ring publish; x-work is gone from the chain (R4's ~1.3k cyc/step).
// Ring handoff unchanged from R4: (fp32<<32)|tag words, relaxed agent atomics,
// depth-4 ring, no fences, no init (0xAA poison != tags 1..1024).
// Fallback: if ws_size < ring+gx (269 MB), launch the proven R4 kernel.

#define T_STEPS 1024
#define BATCH   32
#define IDIM    512
#define HDIM    512

#define BG      4
#define JG      64
#define NBLK    (BG*JG)
#define BPB     (BATCH/BG)    // 8 batches/block
#define JPB     (HDIM/JG)     // 8 hidden units/block
#define RPB     (4*JPB)       // 32 gate rows/block
#define NTHR    256
#define PSTRIDE 257
#define HWORDS  (BPB*HDIM)    // 4096 tagged words per (slot,bg)
#define WPT     (HWORDS/NTHR) // 16 words per consumer thread
#define RING_BYTES  ((size_t)4 * BG * HWORDS * 8)          // 512 KB
#define GX_PER_BLK  ((size_t)T_STEPS * NTHR)               // 262144 floats
#define GX_BYTES    ((size_t)NBLK * GX_PER_BLK * 4)        // 256 MB

__device__ __forceinline__ float sigmoid_f(float v) {
    return 1.0f / (1.0f + __expf(-v));
}
__device__ __forceinline__ float tanh_f(float v) {
    float e = __expf(2.0f * v);
    return 1.0f - 2.0f / (e + 1.0f);
}

// ---------------------------------------------------------------- two-phase
__global__ __launch_bounds__(NTHR, 1) void lstm_two_phase(
    const float* __restrict__ x, const float* __restrict__ h0,
    const float* __restrict__ c0, const float* __restrict__ Wih,
    const float* __restrict__ Whh, const float* __restrict__ bih,
    const float* __restrict__ bhh, float* __restrict__ out,
    unsigned long long* __restrict__ ring,   // d_ws + 0
    float* __restrict__ gxws)                // d_ws + 512 KB, 1 MB/block private
{
    __shared__ __align__(16) float tile[BPB * IDIM];    // 16 KB (x, then h)
    __shared__ float part[RPB * PSTRIDE];               // 32.9 KB
    __shared__ float garr[RPB * 9];
    __shared__ float biasl[RPB];

    const int tid = threadIdx.x;
    const int bid = blockIdx.x;
    const int bg  = bid >> 6;
    const int jg  = bid & 63;
    const int ks  = tid >> 3;        // 0..31 k-slice
    const int rq  = tid & 7;         // 0..7  row-quad

    float* gxp = gxws + (size_t)bid * GX_PER_BLK;   // private slice

    // ---- weight slices -> registers ----
    float4 wih[4][4], whh[4][4];
    #pragma unroll
    for (int r = 0; r < 4; ++r) {
        const int lr = rq * 4 + r;
        const int grow = (lr >> 3) * HDIM + jg * JPB + (lr & 7);
        const float* wi = Wih + (size_t)grow * IDIM;
        const float* wh = Whh + (size_t)grow * HDIM;
        #pragma unroll
        for (int j = 0; j < 4; ++j) {
            const int k = ks * 4 + j * 128;
            wih[r][j] = *(const float4*)(wi + k);
            whh[r][j] = *(const float4*)(wh + k);
        }
    }
    if (tid < RPB) {
        const int grow = (tid >> 3) * HDIM + jg * JPB + (tid & 7);
        biasl[tid] = bih[grow] + bhh[grow];
    }
    const int ab = tid >> 2;          // act thread batch (tid<32)
    const int j0 = (tid & 3) * 2;
    float cst0 = 0.f, cst1 = 0.f, hl0 = 0.f, hl1 = 0.f;
    if (tid < 32) {
        const size_t coff = (size_t)(bg * BPB + ab) * HDIM + jg * JPB + j0;
        cst0 = c0[coff];
        cst1 = c0[coff + 1];
    }
    __syncthreads();

    // ================= phase 0: private gx precompute (no sync) ==========
    for (int t = 0; t < T_STEPS; ++t) {
        const float* xsrc = x + ((size_t)t * BATCH + bg * BPB) * IDIM;
        #pragma unroll
        for (int i = 0; i < 4; ++i) {
            const int f = i * 1024 + tid * 4;
            *(float4*)(tile + f) = *(const float4*)(xsrc + f);
        }
        __syncthreads();                              // A: tile ready

        float acc[4][BPB];
        #pragma unroll
        for (int r = 0; r < 4; ++r)
            #pragma unroll
            for (int b = 0; b < BPB; ++b) acc[r][b] = 0.0f;
        #pragma unroll
        for (int j = 0; j < 4; ++j) {
            #pragma unroll
            for (int b = 0; b < BPB; ++b) {
                const float4 vx = *(const float4*)(tile + b * IDIM + ks * 4 + j * 128);
                #pragma unroll
                for (int r = 0; r < 4; ++r) {
                    acc[r][b] = fmaf(wih[r][j].x, vx.x, acc[r][b]);
                    acc[r][b] = fmaf(wih[r][j].y, vx.y, acc[r][b]);
                    acc[r][b] = fmaf(wih[r][j].z, vx.z, acc[r][b]);
                    acc[r][b] = fmaf(wih[r][j].w, vx.w, acc[r][b]);
                }
            }
        }
        #pragma unroll
        for (int r = 0; r < 4; ++r) {
            const int lr = rq * 4 + r;
            #pragma unroll
            for (int b = 0; b < BPB; ++b)
                part[lr * PSTRIDE + b * 32 + ks] = acc[r][b];
        }
        __syncthreads();                              // E: partials ready

        {   // reduce -> gx store (thread tid owns (b=tid>>5, lr=tid&31))
            const int b  = tid >> 5;
            const int lr = tid & 31;
            const float* p = part + lr * PSTRIDE + b * 32;
            float s0 = 0.f, s1 = 0.f, s2 = 0.f, s3 = 0.f;
            #pragma unroll
            for (int k2 = 0; k2 < 32; k2 += 4) {
                s0 += p[k2]; s1 += p[k2 + 1]; s2 += p[k2 + 2]; s3 += p[k2 + 3];
            }
            gxp[t * NTHR + tid] = (s0 + s1) + (s2 + s3) + biasl[lr];
        }
        __syncthreads();                              // G: part/tile reuse
    }

    // ================= phase 1: slim recurrence ==========================
    for (int t = 0; t < T_STEPS; ++t) {
        // gx for this step (private, plain load; used ~2k cycles later)
        const float gxv = gxp[t * NTHR + tid];

        // prefetch tagged h(t-1) words
        unsigned long long v[WPT];
        const unsigned int tag = (unsigned int)t;
        const unsigned long long* rb =
            ring + ((size_t)((t - 1) & 3) * BG + bg) * HWORDS;
        if (t > 0) {
            #pragma unroll
            for (int w = 0; w < WPT; ++w)
                v[w] = __hip_atomic_load(rb + w * NTHR + tid,
                                         __ATOMIC_RELAXED,
                                         __HIP_MEMORY_SCOPE_AGENT);
            for (int sweep = 0; sweep < 30000; ++sweep) {
                bool ok = true;
                #pragma unroll
                for (int w = 0; w < WPT; ++w) {
                    if ((unsigned int)v[w] != tag) {
                        v[w] = __hip_atomic_load(rb + w * NTHR + tid,
                                                 __ATOMIC_RELAXED,
                                                 __HIP_MEMORY_SCOPE_AGENT);
                        ok = false;
                    }
                }
                if (ok) break;
                __builtin_amdgcn_s_sleep(1);
            }
            #pragma unroll
            for (int w = 0; w < WPT; ++w)
                tile[w * NTHR + tid] =
                    __uint_as_float((unsigned int)(v[w] >> 32));
        } else {
            const float* hsrc = h0 + (size_t)bg * BPB * HDIM;
            #pragma unroll
            for (int i = 0; i < 4; ++i) {
                const int f = i * 1024 + tid * 4;
                *(float4*)(tile + f) = *(const float4*)(hsrc + f);
            }
        }
        __syncthreads();                              // D: htile ready

        float acc[4][BPB];
        #pragma unroll
        for (int r = 0; r < 4; ++r)
            #pragma unroll
            for (int b = 0; b < BPB; ++b) acc[r][b] = 0.0f;
        #pragma unroll
        for (int j = 0; j < 4; ++j) {
            #pragma unroll
            for (int b = 0; b < BPB; ++b) {
                const float4 vh = *(const float4*)(tile + b * HDIM + ks * 4 + j * 128);
                #pragma unroll
                for (int r = 0; r < 4; ++r) {
                    acc[r][b] = fmaf(whh[r][j].x, vh.x, acc[r][b]);
                    acc[r][b] = fmaf(whh[r][j].y, vh.y, acc[r][b]);
                    acc[r][b] = fmaf(whh[r][j].z, vh.z, acc[r][b]);
                    acc[r][b] = fmaf(whh[r][j].w, vh.w, acc[r][b]);
                }
            }
        }
        #pragma unroll
        for (int r = 0; r < 4; ++r) {
            const int lr = rq * 4 + r;
            #pragma unroll
            for (int b = 0; b < BPB; ++b)
                part[lr * PSTRIDE + b * 32 + ks] = acc[r][b];
        }
        __syncthreads();                              // E

        {   // reduce + gx  (same (b,lr)=tid mapping as the gx store)
            const int b  = tid >> 5;
            const int lr = tid & 31;
            const float* p = part + lr * PSTRIDE + b * 32;
            float s0 = 0.f, s1 = 0.f, s2 = 0.f, s3 = 0.f;
            #pragma unroll
            for (int k2 = 0; k2 < 32; k2 += 4) {
                s0 += p[k2]; s1 += p[k2 + 1]; s2 += p[k2 + 2]; s3 += p[k2 + 3];
            }
            garr[lr * 9 + b] = (s0 + s1) + (s2 + s3) + gxv;
        }
        __syncthreads();                              // F

        if (tid < 32) {
            const float i0 = sigmoid_f(garr[(0 * 8 + j0    ) * 9 + ab]);
            const float f0 = sigmoid_f(garr[(1 * 8 + j0    ) * 9 + ab]);
            const float g0 = tanh_f  (garr[(2 * 8 + j0    ) * 9 + ab]);
            const float o0 = sigmoid_f(garr[(3 * 8 + j0    ) * 9 + ab]);
            const float i1 = sigmoid_f(garr[(0 * 8 + j0 + 1) * 9 + ab]);
            const float f1 = sigmoid_f(garr[(1 * 8 + j0 + 1) * 9 + ab]);
            const float g1 = tanh_f  (garr[(2 * 8 + j0 + 1) * 9 + ab]);
            const float o1 = sigmoid_f(garr[(3 * 8 + j0 + 1) * 9 + ab]);
            cst0 = fmaf(f0, cst0, i0 * g0);
            cst1 = fmaf(f1, cst1, i1 * g1);
            hl0  = o0 * tanh_f(cst0);
            hl1  = o1 * tanh_f(cst1);

            union { float f[2]; unsigned long long q; } u;
            u.f[0] = hl0; u.f[1] = hl1;
            *(unsigned long long*)(out + ((size_t)t * BATCH + bg * BPB + ab) * HDIM
                                       + jg * JPB + j0) = u.q;

            const unsigned long long tg = (unsigned long long)(t + 1);
            unsigned long long* rw = ring
                + ((size_t)(t & 3) * BG + bg) * HWORDS
                + ab * HDIM + jg * JPB + j0;
            __hip_atomic_store(rw,
                (((unsigned long long)__float_as_uint(hl0)) << 32) | tg,
                __ATOMIC_RELAXED, __HIP_MEMORY_SCOPE_AGENT);
            __hip_atomic_store(rw + 1,
                (((unsigned long long)__float_as_uint(hl1)) << 32) | tg,
                __ATOMIC_RELAXED, __HIP_MEMORY_SCOPE_AGENT);
        }
        // no extra barrier: D/E/F separate all cross-step hazards
    }

    if (tid < 32) {
        const size_t base = (size_t)T_STEPS * BATCH * HDIM;
        const size_t off  = (size_t)(bg * BPB + ab) * HDIM + jg * JPB + j0;
        out[base + off]     = hl0;
        out[base + off + 1] = hl1;
        out[base + (size_t)BATCH * HDIM + off]     = cst0;
        out[base + (size_t)BATCH * HDIM + off + 1] = cst1;
    }
}

// ------------------------------------------------- fallback (R4, proven)
__global__ __launch_bounds__(NTHR, 1) void lstm_fused(
    const float* __restrict__ x, const float* __restrict__ h0,
    const float* __restrict__ c0, const float* __restrict__ Wih,
    const float* __restrict__ Whh, const float* __restrict__ bih,
    const float* __restrict__ bhh, float* __restrict__ out,
    unsigned long long* __restrict__ ring)
{
    __shared__ __align__(16) float xtile[BPB * IDIM];
    __shared__ __align__(16) float htile[BPB * HDIM];
    __shared__ float part[RPB * PSTRIDE];
    __shared__ float garr[RPB * 9];
    __shared__ float biasl[RPB];

    const int tid = threadIdx.x;
    const int bid = blockIdx.x;
    const int bg  = bid >> 6;
    const int jg  = bid & 63;
    const int ks  = tid >> 3;
    const int rq  = tid & 7;

    float4 wih[4][4], whh[4][4];
    #pragma unroll
    for (int r = 0; r < 4; ++r) {
        const int lr = rq * 4 + r;
        const int grow = (lr >> 3) * HDIM + jg * JPB + (lr & 7);
        const float* wi = Wih + (size_t)grow * IDIM;
        const float* wh = Whh + (size_t)grow * HDIM;
        #pragma unroll
        for (int j = 0; j < 4; ++j) {
            const int k = ks * 4 + j * 128;
            wih[r][j] = *(const float4*)(wi + k);
            whh[r][j] = *(const float4*)(wh + k);
        }
    }
    if (tid < RPB) {
        const int grow = (tid >> 3) * HDIM + jg * JPB + (tid & 7);
        biasl[tid] = bih[grow] + bhh[grow];
    }
    const int ab = tid >> 2;
    const int j0 = (tid & 3) * 2;
    float cst0 = 0.f, cst1 = 0.f, hl0 = 0.f, hl1 = 0.f;
    if (tid < 32) {
        const size_t coff = (size_t)(bg * BPB + ab) * HDIM + jg * JPB + j0;
        cst0 = c0[coff];
        cst1 = c0[coff + 1];
    }
    __syncthreads();

    for (int t = 0; t < T_STEPS; ++t) {
        {
            const float* xsrc = x + ((size_t)t * BATCH + bg * BPB) * IDIM;
            #pragma unroll
            for (int i = 0; i < 4; ++i) {
                const int f = i * 1024 + tid * 4;
                *(float4*)(xtile + f) = *(const float4*)(xsrc + f);
            }
        }
        __syncthreads();

        unsigned long long v[WPT];
        const unsigned int tag = (unsigned int)t;
        const unsigned long long* rb =
            ring + ((size_t)((t - 1) & 3) * BG + bg) * HWORDS;
        if (t > 0) {
            #pragma unroll
            for (int w = 0; w < WPT; ++w)
                v[w] = __hip_atomic_load(rb + w * NTHR + tid,
                                         __ATOMIC_RELAXED,
                                         __HIP_MEMORY_SCOPE_AGENT);
        }

        float acc[4][BPB];
        #pragma unroll
        for (int r = 0; r < 4; ++r)
            #pragma unroll
            for (int b = 0; b < BPB; ++b) acc[r][b] = 0.0f;
        #pragma unroll
        for (int j = 0; j < 4; ++j) {
            #pragma unroll
            for (int b = 0; b < BPB; ++b) {
                const float4 vx = *(const float4*)(xtile + b * IDIM + ks * 4 + j * 128);
                #pragma unroll
                for (int r = 0; r < 4; ++r) {
                    acc[r][b] = fmaf(wih[r][j].x, vx.x, acc[r][b]);
                    acc[r][b] = fmaf(wih[r][j].y, vx.y, acc[r][b]);
                    acc[r][b] = fmaf(wih[r][j].z, vx.z, acc[r][b]);
                    acc[r][b] = fmaf(wih[r][j].w, vx.w, acc[r][b]);
                }
            }
        }

        if (t > 0) {
            for (int sweep = 0; sweep < 30000; ++sweep) {
                bool ok = true;
                #pragma unroll
                for (int w = 0; w < WPT; ++w) {
                    if ((unsigned int)v[w] != tag) {
                        v[w] = __hip_atomic_load(rb + w * NTHR + tid,
                                                 __ATOMIC_RELAXED,
                                                 __HIP_MEMORY_SCOPE_AGENT);
                        ok = false;
                    }
                }
                if (ok) break;
                __builtin_amdgcn_s_sleep(1);
            }
            #pragma unroll
            for (int w = 0; w < WPT; ++w)
                htile[w * NTHR + tid] =
                    __uint_as_float((unsigned int)(v[w] >> 32));
        } else {
            const float* hsrc = h0 + (size_t)bg * BPB * HDIM;
            #pragma unroll
            for (int i = 0; i < 4; ++i) {
                const int f = i * 1024 + tid * 4;
                *(float4*)(htile + f) = *(const float4*)(hsrc + f);
            }
        }
        __syncthreads();

        #pragma unroll
        for (int j = 0; j < 4; ++j) {
            #pragma unroll
            for (int b = 0; b < BPB; ++b) {
                const float4 vh = *(const float4*)(htile + b * HDIM + ks * 4 + j * 128);
                #pragma unroll
                for (int r = 0; r < 4; ++r) {
                    acc[r][b] = fmaf(whh[r][j].x, vh.x, acc[r][b]);
                    acc[r][b] = fmaf(whh[r][j].y, vh.y, acc[r][b]);
                    acc[r][b] = fmaf(whh[r][j].z, vh.z, acc[r][b]);
                    acc[r][b] = fmaf(whh[r][j].w, vh.w, acc[r][b]);
                }
            }
        }
        #pragma unroll
        for (int r = 0; r < 4; ++r) {
            const int lr = rq * 4 + r;
            #pragma unroll
            for (int b = 0; b < BPB; ++b)
                part[lr * PSTRIDE + b * 32 + ks] = acc[r][b];
        }
        __syncthreads();

        {
            const int b  = tid >> 5;
            const int lr = tid & 31;
            const float* p = part + lr * PSTRIDE + b * 32;
            float s0 = 0.f, s1 = 0.f, s2 = 0.f, s3 = 0.f;
            #pragma unroll
            for (int k2 = 0; k2 < 32; k2 += 4) {
                s0 += p[k2]; s1 += p[k2 + 1]; s2 += p[k2 + 2]; s3 += p[k2 + 3];
            }
            garr[lr * 9 + b] = (s0 + s1) + (s2 + s3) + biasl[lr];
        }
        __syncthreads();

        if (tid < 32) {
            const float i0 = sigmoid_f(garr[(0 * 8 + j0    ) * 9 + ab]);
            const float f0 = sigmoid_f(garr[(1 * 8 + j0    ) * 9 + ab]);
            const float g0 = tanh_f  (garr[(2 * 8 + j0    ) * 9 + ab]);
            const float o0 = sigmoid_f(garr[(3 * 8 + j0    ) * 9 + ab]);
            const float i1 = sigmoid_f(garr[(0 * 8 + j0 + 1) * 9 + ab]);
            const float f1 = sigmoid_f(garr[(1 * 8 + j0 + 1) * 9 + ab]);
            const float g1 = tanh_f  (garr[(2 * 8 + j0 + 1) * 9 + ab]);
            const float o1 = sigmoid_f(garr[(3 * 8 + j0 + 1) * 9 + ab]);
            cst0 = fmaf(f0, cst0, i0 * g0);
            cst1 = fmaf(f1, cst1, i1 * g1);
            hl0  = o0 * tanh_f(cst0);
            hl1  = o1 * tanh_f(cst1);
            union { float f[2]; unsigned long long q; } u;
            u.f[0] = hl0; u.f[1] = hl1;
            *(unsigned long long*)(out + ((size_t)t * BATCH + bg * BPB + ab) * HDIM
                                       + jg * JPB + j0) = u.q;
            const unsigned long long tg = (unsigned long long)(t + 1);
            unsigned long long* rw = ring
                + ((size_t)(t & 3) * BG + bg) * HWORDS
                + ab * HDIM + jg * JPB + j0;
            __hip_atomic_store(rw,
                (((unsigned long long)__float_as_uint(hl0)) << 32) | tg,
                __ATOMIC_RELAXED, __HIP_MEMORY_SCOPE_AGENT);
            __hip_atomic_store(rw + 1,
                (((unsigned long long)__float_as_uint(hl1)) << 32) | tg,
                __ATOMIC_RELAXED, __HIP_MEMORY_SCOPE_AGENT);
        }
    }

    if (tid < 32) {
        const size_t base = (size_t)T_STEPS * BATCH * HDIM;
        const size_t off  = (size_t)(bg * BPB + ab) * HDIM + jg * JPB + j0;
        out[base + off]     = hl0;
        out[base + off + 1] = hl1;
        out[base + (size_t)BATCH * HDIM + off]     = cst0;
        out[base + (size_t)BATCH * HDIM + off + 1] = cst1;
    }
}

extern "C" void kernel_launch(void* const* d_in, const int* in_sizes, int n_in,
                              void* d_out, int out_size, void* d_ws, size_t ws_size,
                              hipStream_t stream) {
    const float* x   = (const float*)d_in[0];
    const float* h0  = (const float*)d_in[1];
    const float* c0  = (const float*)d_in[2];
    const float* Wih = (const float*)d_in[3];
    const float* Whh = (const float*)d_in[4];
    const float* bih = (const float*)d_in[5];
    const float* bhh = (const float*)d_in[6];
    float* out = (float*)d_out;
    unsigned long long* ring = (unsigned long long*)d_ws;

    if (ws_size >= RING_BYTES + GX_BYTES) {
        float* gxws = (float*)((char*)d_ws + RING_BYTES);
        lstm_two_phase<<<dim3(NBLK), dim3(NTHR), 0, stream>>>(
            x, h0, c0, Wih, Whh, bih, bhh, out, ring, gxws);
    } else {
        lstm_fused<<<dim3(NBLK), dim3(NTHR), 0, stream>>>(
            x, h0, c0, Wih, Whh, bih, bhh, out, ring);
    }
}